// Round 3
// baseline (172.043 us; speedup 1.0000x reference)
//
#include <hip/hip_runtime.h>

typedef float  f32x4  __attribute__((ext_vector_type(4)));
typedef short  bf16x8 __attribute__((ext_vector_type(8)));

#define NN 2048
#define CC 64

__device__ __forceinline__ unsigned short f2bf(float f) {
  union { float f; unsigned u; } v; v.f = f;
  unsigned r = v.u + 0x7fffu + ((v.u >> 16) & 1u);
  return (unsigned short)(r >> 16);
}

// ---------------- layer-0 linear: Mt = (X*Wm^T)^T bf16, S = X*Ws^T + b ----------------
__global__ __launch_bounds__(256) void gcn_linear(
    const float* __restrict__ H, const float* __restrict__ Wm,
    const float* __restrict__ Ws, const float* __restrict__ bias,
    unsigned short* __restrict__ Mt, float* __restrict__ S)
{
  const int bid = blockIdx.x;
  const int b   = bid >> 5;
  const int n0  = (bid & 31) << 6;
  const int tid = threadIdx.x;

  __shared__ float4 Hl[1024];
  __shared__ float4 Wm4[1024];
  __shared__ float4 Ws4[1024];

  const float4* Hg  = reinterpret_cast<const float4*>(H + ((size_t)b * NN + n0) * CC);
  const float4* Wmg = reinterpret_cast<const float4*>(Wm);
  const float4* Wsg = reinterpret_cast<const float4*>(Ws);
#pragma unroll
  for (int i = 0; i < 4; ++i) {
    int f = tid + 256 * i;
    Hl[f] = Hg[f];
    int o = f >> 4, c4 = f & 15;
    int slot = (o << 4) | (c4 ^ (o & 15));
    Wm4[slot] = Wmg[f];
    Ws4[slot] = Wsg[f];
  }
  __syncthreads();

  const int o = tid & 63, wv = tid >> 6;
  float accm[16], accs[16];
#pragma unroll
  for (int p = 0; p < 16; ++p) { accm[p] = 0.f; accs[p] = 0.f; }

  for (int c4 = 0; c4 < 16; ++c4) {
    int slot = (o << 4) | (c4 ^ (o & 15));
    float4 wm  = Wm4[slot];
    float4 wsv = Ws4[slot];
#pragma unroll
    for (int p = 0; p < 16; ++p) {
      float4 h = Hl[((wv << 4) + p) * 16 + c4];
      accm[p] += h.x * wm.x  + h.y * wm.y  + h.z * wm.z  + h.w * wm.w;
      accs[p] += h.x * wsv.x + h.y * wsv.y + h.z * wsv.z + h.w * wsv.w;
    }
  }

  const float bv = bias[o];
#pragma unroll
  for (int p = 0; p < 16; ++p) {
    int r = n0 + (wv << 4) + p;
    Mt[((size_t)b * CC + o) * NN + r] = f2bf(accm[p]);
    S [((size_t)b * NN + r) * CC + o] = accs[p] + bv;
  }
}

// -------- fused linear (layers 1,2): H = relu(sum Part + S) in-reg -> Mt, Sout --------
__global__ __launch_bounds__(256) void gcn_linear_fused(
    const float* __restrict__ Part, const float* __restrict__ Sin,
    const float* __restrict__ Wm, const float* __restrict__ Ws,
    const float* __restrict__ bias,
    unsigned short* __restrict__ Mt, float* __restrict__ Sout)
{
  const int bid = blockIdx.x;
  const int b   = bid >> 5;
  const int n0  = (bid & 31) << 6;
  const int tid = threadIdx.x;

  __shared__ float4 Hl[1024];
  __shared__ float4 Wm4[1024];
  __shared__ float4 Ws4[1024];

  const size_t base = ((size_t)b * NN + n0) * CC / 4;    // float4 index
  const size_t cstr = (size_t)8 * NN * CC / 4;           // per-chunk float4 stride
  const float4* Pg  = reinterpret_cast<const float4*>(Part);
  const float4* Sg  = reinterpret_cast<const float4*>(Sin);
  const float4* Wmg = reinterpret_cast<const float4*>(Wm);
  const float4* Wsg = reinterpret_cast<const float4*>(Ws);
#pragma unroll
  for (int i = 0; i < 4; ++i) {
    int f = tid + 256 * i;
    float4 p0 = Pg[base + f];
    float4 p1 = Pg[base + cstr + f];
    float4 p2 = Pg[base + 2 * cstr + f];
    float4 p3 = Pg[base + 3 * cstr + f];
    float4 s  = Sg[base + f];
    float4 h;
    h.x = fmaxf(p0.x + p1.x + p2.x + p3.x + s.x, 0.f);
    h.y = fmaxf(p0.y + p1.y + p2.y + p3.y + s.y, 0.f);
    h.z = fmaxf(p0.z + p1.z + p2.z + p3.z + s.z, 0.f);
    h.w = fmaxf(p0.w + p1.w + p2.w + p3.w + s.w, 0.f);
    Hl[f] = h;
    int o = f >> 4, c4 = f & 15;
    int slot = (o << 4) | (c4 ^ (o & 15));
    Wm4[slot] = Wmg[f];
    Ws4[slot] = Wsg[f];
  }
  __syncthreads();

  const int o = tid & 63, wv = tid >> 6;
  float accm[16], accs[16];
#pragma unroll
  for (int p = 0; p < 16; ++p) { accm[p] = 0.f; accs[p] = 0.f; }

  for (int c4 = 0; c4 < 16; ++c4) {
    int slot = (o << 4) | (c4 ^ (o & 15));
    float4 wm  = Wm4[slot];
    float4 wsv = Ws4[slot];
#pragma unroll
    for (int p = 0; p < 16; ++p) {
      float4 h = Hl[((wv << 4) + p) * 16 + c4];
      accm[p] += h.x * wm.x  + h.y * wm.y  + h.z * wm.z  + h.w * wm.w;
      accs[p] += h.x * wsv.x + h.y * wsv.y + h.z * wsv.z + h.w * wsv.w;
    }
  }

  const float bv = bias[o];
#pragma unroll
  for (int p = 0; p < 16; ++p) {
    int r = n0 + (wv << 4) + p;
    Mt[((size_t)b * CC + o) * NN + r] = f2bf(accm[p]);
    Sout[((size_t)b * NN + r) * CC + o] = accs[p] + bv;
  }
}

// ---------------- final: out = sum Part + S (no relu) ----------------
__global__ __launch_bounds__(256) void gcn_finalize(
    const float* __restrict__ Part, const float* __restrict__ S,
    float* __restrict__ Out)
{
  const size_t i = (size_t)blockIdx.x * 256 + threadIdx.x;
  const size_t cstr = (size_t)8 * NN * CC / 4;
  const float4* P  = reinterpret_cast<const float4*>(Part);
  const float4* S4 = reinterpret_cast<const float4*>(S);
  float4 p0 = P[i], p1 = P[i + cstr], p2 = P[i + 2 * cstr], p3 = P[i + 3 * cstr];
  float4 s = S4[i], o;
  o.x = p0.x + p1.x + p2.x + p3.x + s.x;
  o.y = p0.y + p1.y + p2.y + p3.y + s.y;
  o.z = p0.z + p1.z + p2.z + p3.z + s.z;
  o.w = p0.w + p1.w + p2.w + p3.w + s.w;
  reinterpret_cast<float4*>(Out)[i] = o;
}

// epilogue: C/D layout col=lane&15, row=(lane>>4)*4+reg  [measured m89/m91]
template<int NSPLIT>
__device__ __forceinline__ void gcn_epilogue(
    f32x4* acc, const float* __restrict__ S, float* __restrict__ Out,
    int b, int chunk, int i0, int w, int fr, int g, int relu)
{
  const int rbase = i0 + (w << 4) + (g << 2);
  if constexpr (NSPLIT == 1) {
#pragma unroll
    for (int n = 0; n < 4; ++n) {
      const int col = (n << 4) | fr;
#pragma unroll
      for (int r = 0; r < 4; ++r) {
        const size_t idx = ((size_t)b * NN + (rbase + r)) * CC + col;
        float v = acc[n][r] + S[idx];
        if (relu) v = fmaxf(v, 0.f);
        Out[idx] = v;
      }
    }
  } else {
    float* P = Out + ((size_t)(chunk * 8 + b) * NN) * CC;
#pragma unroll
    for (int n = 0; n < 4; ++n) {
      const int col = (n << 4) | fr;
#pragma unroll
      for (int r = 0; r < 4; ++r)
        P[(size_t)(rbase + r) * CC + col] = acc[n][r];
    }
  }
}

// ---------------- GEMM, fp32 A (layer 0 / fallback), optional bf16-A side-store ----------------
template<int NSPLIT>
__global__ __launch_bounds__(256) void gcn_gemm_f32(
    const float* __restrict__ A, const unsigned short* __restrict__ Mt,
    const float* __restrict__ S, float* __restrict__ Out,
    unsigned short* __restrict__ Abf, const int relu)
{
  constexpr int ITERS = NN / (64 * NSPLIT);
  const int bid = blockIdx.x;
  const int b   = bid & 7;                 // batch == XCD (Mt L2 locality)
  const int idx = bid >> 3;
  const int i0  = (idx & 31) << 6;
  const int chunk = idx >> 5;
  const int j0base = chunk * (NN / NSPLIT);
  const int tid = threadIdx.x, lane = tid & 63, w = tid >> 6;
  const int fr = lane & 15, g = lane >> 4;
  const int row = i0 + (w << 4) + fr;

  const float* ap = A + ((size_t)b * NN + row) * NN + j0base + (g << 3);
  const unsigned short* Mb = Mt + (size_t)b * CC * NN + (size_t)fr * NN + j0base + (g << 3);
  const bool wr = (Abf != nullptr);
  unsigned short* abp = wr ? (Abf + ((size_t)b * NN + row) * NN + j0base + (g << 3)) : nullptr;

  f32x4 acc[4];
#pragma unroll
  for (int n = 0; n < 4; ++n) acc[n] = (f32x4){0.f, 0.f, 0.f, 0.f};

  float4 A0[4], A1[4];
  bf16x8 B0[8];
#pragma unroll
  for (int i = 0; i < 2; ++i) {
    A0[2*i+0] = *reinterpret_cast<const float4*>(ap + 32*i + 0);
    A0[2*i+1] = *reinterpret_cast<const float4*>(ap + 32*i + 4);
    A1[2*i+0] = *reinterpret_cast<const float4*>(ap + 64 + 32*i + 0);
    A1[2*i+1] = *reinterpret_cast<const float4*>(ap + 64 + 32*i + 4);
  }
#pragma unroll
  for (int kk = 0; kk < 2; ++kk)
#pragma unroll
    for (int n = 0; n < 4; ++n)
      B0[kk*4+n] = *reinterpret_cast<const bf16x8*>(Mb + (size_t)(n << 4) * NN + (kk << 5));

  for (int t = 0; t < ITERS; ++t) {
    float4 A2[4]; bf16x8 B1[8];
    if (t < ITERS - 2) {
      const float* q = ap + (size_t)(t + 2) * 64;
#pragma unroll
      for (int i = 0; i < 2; ++i) {
        A2[2*i+0] = *reinterpret_cast<const float4*>(q + 32*i + 0);
        A2[2*i+1] = *reinterpret_cast<const float4*>(q + 32*i + 4);
      }
    }
    if (t < ITERS - 1) {
      const unsigned short* mq = Mb + ((t + 1) << 6);
#pragma unroll
      for (int kk = 0; kk < 2; ++kk)
#pragma unroll
        for (int n = 0; n < 4; ++n)
          B1[kk*4+n] = *reinterpret_cast<const bf16x8*>(mq + (size_t)(n << 4) * NN + (kk << 5));
    }

    bf16x8 af[2];
#pragma unroll
    for (int kk = 0; kk < 2; ++kk) {
      af[kk][0] = (short)f2bf(A0[2*kk+0].x);
      af[kk][1] = (short)f2bf(A0[2*kk+0].y);
      af[kk][2] = (short)f2bf(A0[2*kk+0].z);
      af[kk][3] = (short)f2bf(A0[2*kk+0].w);
      af[kk][4] = (short)f2bf(A0[2*kk+1].x);
      af[kk][5] = (short)f2bf(A0[2*kk+1].y);
      af[kk][6] = (short)f2bf(A0[2*kk+1].z);
      af[kk][7] = (short)f2bf(A0[2*kk+1].w);
    }
    if (wr) {
      *reinterpret_cast<bf16x8*>(abp + t * 64)      = af[0];
      *reinterpret_cast<bf16x8*>(abp + t * 64 + 32) = af[1];
    }
#pragma unroll
    for (int kk = 0; kk < 2; ++kk)
#pragma unroll
      for (int n = 0; n < 4; ++n)
        acc[n] = __builtin_amdgcn_mfma_f32_16x16x32_bf16(af[kk], B0[kk*4+n], acc[n], 0, 0, 0);
#pragma unroll
    for (int i = 0; i < 4; ++i) { A0[i] = A1[i]; A1[i] = A2[i]; }
#pragma unroll
    for (int i = 0; i < 8; ++i) B0[i] = B1[i];
  }

  gcn_epilogue<NSPLIT>(acc, S, Out, b, chunk, i0, w, fr, g, relu);
}

// ---------------- GEMM, bf16 A (layers 1,2) ----------------
template<int NSPLIT>
__global__ __launch_bounds__(256) void gcn_gemm_bf16(
    const unsigned short* __restrict__ Abf, const unsigned short* __restrict__ Mt,
    const float* __restrict__ S, float* __restrict__ Out, const int relu)
{
  constexpr int ITERS = NN / (64 * NSPLIT);
  const int bid = blockIdx.x;
  const int b   = bid & 7;
  const int idx = bid >> 3;
  const int i0  = (idx & 31) << 6;
  const int chunk = idx >> 5;
  const int j0base = chunk * (NN / NSPLIT);
  const int tid = threadIdx.x, lane = tid & 63, w = tid >> 6;
  const int fr = lane & 15, g = lane >> 4;
  const int row = i0 + (w << 4) + fr;

  const unsigned short* ap = Abf + ((size_t)b * NN + row) * NN + j0base + (g << 3);
  const unsigned short* Mb = Mt + (size_t)b * CC * NN + (size_t)fr * NN + j0base + (g << 3);

  f32x4 acc[4];
#pragma unroll
  for (int n = 0; n < 4; ++n) acc[n] = (f32x4){0.f, 0.f, 0.f, 0.f};

  bf16x8 A0[2], A1[2], B0[8];
  A0[0] = *reinterpret_cast<const bf16x8*>(ap + 0);
  A0[1] = *reinterpret_cast<const bf16x8*>(ap + 32);
  A1[0] = *reinterpret_cast<const bf16x8*>(ap + 64);
  A1[1] = *reinterpret_cast<const bf16x8*>(ap + 96);
#pragma unroll
  for (int kk = 0; kk < 2; ++kk)
#pragma unroll
    for (int n = 0; n < 4; ++n)
      B0[kk*4+n] = *reinterpret_cast<const bf16x8*>(Mb + (size_t)(n << 4) * NN + (kk << 5));

  for (int t = 0; t < ITERS; ++t) {
    bf16x8 A2[2], B1[8];
    if (t < ITERS - 2) {
      const unsigned short* q = ap + (size_t)(t + 2) * 64;
      A2[0] = *reinterpret_cast<const bf16x8*>(q + 0);
      A2[1] = *reinterpret_cast<const bf16x8*>(q + 32);
    }
    if (t < ITERS - 1) {
      const unsigned short* mq = Mb + ((t + 1) << 6);
#pragma unroll
      for (int kk = 0; kk < 2; ++kk)
#pragma unroll
        for (int n = 0; n < 4; ++n)
          B1[kk*4+n] = *reinterpret_cast<const bf16x8*>(mq + (size_t)(n << 4) * NN + (kk << 5));
    }
#pragma unroll
    for (int kk = 0; kk < 2; ++kk)
#pragma unroll
      for (int n = 0; n < 4; ++n)
        acc[n] = __builtin_amdgcn_mfma_f32_16x16x32_bf16(A0[kk], B0[kk*4+n], acc[n], 0, 0, 0);
#pragma unroll
    for (int i = 0; i < 2; ++i) { A0[i] = A1[i]; A1[i] = A2[i]; }
#pragma unroll
    for (int i = 0; i < 8; ++i) B0[i] = B1[i];
  }

  gcn_epilogue<NSPLIT>(acc, S, Out, b, chunk, i0, w, fr, g, relu);
}

extern "C" void kernel_launch(void* const* d_in, const int* in_sizes, int n_in,
                              void* d_out, int out_size, void* d_ws, size_t ws_size,
                              hipStream_t stream)
{
  const float* X = (const float*)d_in[0];
  const float* A = (const float*)d_in[1];
  const size_t MB = 1024 * 1024;
  unsigned short* Mt = (unsigned short*)d_ws;                 // 2 MiB
  float* S   = (float*)((char*)d_ws + 2 * MB);                // 4 MiB
  float* Prt = (float*)((char*)d_ws + 6 * MB);                // 16 MiB (4 chunks)
  unsigned short* Abf = (unsigned short*)((char*)d_ws + 22 * MB); // 64 MiB

  const bool has_part = ws_size >= 22 * MB;
  const bool has_abf  = ws_size >= 86 * MB;

  if (has_part) {
    for (int l = 0; l < 3; ++l) {
      const float* Wm = (const float*)d_in[2 + 3 * l];
      const float* Ws = (const float*)d_in[3 + 3 * l];
      const float* bb = (const float*)d_in[4 + 3 * l];
      if (l == 0)
        gcn_linear<<<dim3(256), dim3(256), 0, stream>>>(X, Wm, Ws, bb, Mt, S);
      else
        gcn_linear_fused<<<dim3(256), dim3(256), 0, stream>>>(Prt, S, Wm, Ws, bb, Mt, S);
      if (l == 0 && has_abf)
        gcn_gemm_f32<4><<<dim3(1024), dim3(256), 0, stream>>>(A, Mt, S, Prt, Abf, 0);
      else if (has_abf)
        gcn_gemm_bf16<4><<<dim3(1024), dim3(256), 0, stream>>>(Abf, Mt, S, Prt, 0);
      else
        gcn_gemm_f32<4><<<dim3(1024), dim3(256), 0, stream>>>(A, Mt, S, Prt, nullptr, 0);
    }
    gcn_finalize<<<dim3(1024), dim3(256), 0, stream>>>(Prt, S, (float*)d_out);
  } else {
    // small-ws fallback: non-split path (R1 behavior)
    float* H = (float*)d_out;
    for (int l = 0; l < 3; ++l) {
      const float* Wm = (const float*)d_in[2 + 3 * l];
      const float* Ws = (const float*)d_in[3 + 3 * l];
      const float* bb = (const float*)d_in[4 + 3 * l];
      const float* src = (l == 0) ? X : H;
      gcn_linear<<<dim3(256), dim3(256), 0, stream>>>(src, Wm, Ws, bb, Mt, S);
      gcn_gemm_f32<1><<<dim3(256), dim3(256), 0, stream>>>(
          A, Mt, S, H, nullptr, (l < 2) ? 1 : 0);
    }
  }
}

// Round 4
// 170.435 us; speedup vs baseline: 1.0094x; 1.0094x over previous
//
#include <hip/hip_runtime.h>

typedef float  f32x4  __attribute__((ext_vector_type(4)));
typedef short  bf16x8 __attribute__((ext_vector_type(8)));

#define NN 2048
#define CC 64

__device__ __forceinline__ unsigned short f2bf(float f) {
  union { float f; unsigned u; } v; v.f = f;
  unsigned r = v.u + 0x7fffu + ((v.u >> 16) & 1u);
  return (unsigned short)(r >> 16);
}

// ---------------- layer-0 linear: Mt = (X*Wm^T)^T bf16, S = X*Ws^T + b ----------------
__global__ __launch_bounds__(256) void gcn_linear(
    const float* __restrict__ H, const float* __restrict__ Wm,
    const float* __restrict__ Ws, const float* __restrict__ bias,
    unsigned short* __restrict__ Mt, float* __restrict__ S)
{
  const int bid = blockIdx.x;
  const int b   = bid >> 5;
  const int n0  = (bid & 31) << 6;
  const int tid = threadIdx.x;

  __shared__ float4 Hl[1024];
  __shared__ float4 Wm4[1024];
  __shared__ float4 Ws4[1024];

  const float4* Hg  = reinterpret_cast<const float4*>(H + ((size_t)b * NN + n0) * CC);
  const float4* Wmg = reinterpret_cast<const float4*>(Wm);
  const float4* Wsg = reinterpret_cast<const float4*>(Ws);
#pragma unroll
  for (int i = 0; i < 4; ++i) {
    int f = tid + 256 * i;
    Hl[f] = Hg[f];
    int o = f >> 4, c4 = f & 15;
    int slot = (o << 4) | (c4 ^ (o & 15));
    Wm4[slot] = Wmg[f];
    Ws4[slot] = Wsg[f];
  }
  __syncthreads();

  const int o = tid & 63, wv = tid >> 6;
  float accm[16], accs[16];
#pragma unroll
  for (int p = 0; p < 16; ++p) { accm[p] = 0.f; accs[p] = 0.f; }

  for (int c4 = 0; c4 < 16; ++c4) {
    int slot = (o << 4) | (c4 ^ (o & 15));
    float4 wm  = Wm4[slot];
    float4 wsv = Ws4[slot];
#pragma unroll
    for (int p = 0; p < 16; ++p) {
      float4 h = Hl[((wv << 4) + p) * 16 + c4];
      accm[p] += h.x * wm.x  + h.y * wm.y  + h.z * wm.z  + h.w * wm.w;
      accs[p] += h.x * wsv.x + h.y * wsv.y + h.z * wsv.z + h.w * wsv.w;
    }
  }

  const float bv = bias[o];
#pragma unroll
  for (int p = 0; p < 16; ++p) {
    int r = n0 + (wv << 4) + p;
    Mt[((size_t)b * CC + o) * NN + r] = f2bf(accm[p]);
    S [((size_t)b * NN + r) * CC + o] = accs[p] + bv;
  }
}

// -------- fused linear (layers 1,2): H = relu(sum Part + S) in-reg -> Mt, Sout --------
__global__ __launch_bounds__(256) void gcn_linear_fused(
    const float* __restrict__ Part, const float* __restrict__ Sin,
    const float* __restrict__ Wm, const float* __restrict__ Ws,
    const float* __restrict__ bias,
    unsigned short* __restrict__ Mt, float* __restrict__ Sout)
{
  const int bid = blockIdx.x;
  const int b   = bid >> 5;
  const int n0  = (bid & 31) << 6;
  const int tid = threadIdx.x;

  __shared__ float4 Hl[1024];
  __shared__ float4 Wm4[1024];
  __shared__ float4 Ws4[1024];

  const size_t base = ((size_t)b * NN + n0) * CC / 4;
  const size_t cstr = (size_t)8 * NN * CC / 4;
  const float4* Pg  = reinterpret_cast<const float4*>(Part);
  const float4* Sg  = reinterpret_cast<const float4*>(Sin);
  const float4* Wmg = reinterpret_cast<const float4*>(Wm);
  const float4* Wsg = reinterpret_cast<const float4*>(Ws);
#pragma unroll
  for (int i = 0; i < 4; ++i) {
    int f = tid + 256 * i;
    float4 p0 = Pg[base + f];
    float4 p1 = Pg[base + cstr + f];
    float4 p2 = Pg[base + 2 * cstr + f];
    float4 p3 = Pg[base + 3 * cstr + f];
    float4 s  = Sg[base + f];
    float4 h;
    h.x = fmaxf(p0.x + p1.x + p2.x + p3.x + s.x, 0.f);
    h.y = fmaxf(p0.y + p1.y + p2.y + p3.y + s.y, 0.f);
    h.z = fmaxf(p0.z + p1.z + p2.z + p3.z + s.z, 0.f);
    h.w = fmaxf(p0.w + p1.w + p2.w + p3.w + s.w, 0.f);
    Hl[f] = h;
    int o = f >> 4, c4 = f & 15;
    int slot = (o << 4) | (c4 ^ (o & 15));
    Wm4[slot] = Wmg[f];
    Ws4[slot] = Wsg[f];
  }
  __syncthreads();

  const int o = tid & 63, wv = tid >> 6;
  float accm[16], accs[16];
#pragma unroll
  for (int p = 0; p < 16; ++p) { accm[p] = 0.f; accs[p] = 0.f; }

  for (int c4 = 0; c4 < 16; ++c4) {
    int slot = (o << 4) | (c4 ^ (o & 15));
    float4 wm  = Wm4[slot];
    float4 wsv = Ws4[slot];
#pragma unroll
    for (int p = 0; p < 16; ++p) {
      float4 h = Hl[((wv << 4) + p) * 16 + c4];
      accm[p] += h.x * wm.x  + h.y * wm.y  + h.z * wm.z  + h.w * wm.w;
      accs[p] += h.x * wsv.x + h.y * wsv.y + h.z * wsv.z + h.w * wsv.w;
    }
  }

  const float bv = bias[o];
#pragma unroll
  for (int p = 0; p < 16; ++p) {
    int r = n0 + (wv << 4) + p;
    Mt[((size_t)b * CC + o) * NN + r] = f2bf(accm[p]);
    Sout[((size_t)b * NN + r) * CC + o] = accs[p] + bv;
  }
}

// ---------------- final: out = sum Part + S (no relu) ----------------
__global__ __launch_bounds__(256) void gcn_finalize(
    const float* __restrict__ Part, const float* __restrict__ S,
    float* __restrict__ Out)
{
  const size_t i = (size_t)blockIdx.x * 256 + threadIdx.x;
  const size_t cstr = (size_t)8 * NN * CC / 4;
  const float4* P  = reinterpret_cast<const float4*>(Part);
  const float4* S4 = reinterpret_cast<const float4*>(S);
  float4 p0 = P[i], p1 = P[i + cstr], p2 = P[i + 2 * cstr], p3 = P[i + 3 * cstr];
  float4 s = S4[i], o;
  o.x = p0.x + p1.x + p2.x + p3.x + s.x;
  o.y = p0.y + p1.y + p2.y + p3.y + s.y;
  o.z = p0.z + p1.z + p2.z + p3.z + s.z;
  o.w = p0.w + p1.w + p2.w + p3.w + s.w;
  reinterpret_cast<float4*>(Out)[i] = o;
}

// epilogue: C/D layout col=lane&15, row=(lane>>4)*4+reg  [measured m89/m91]
template<int NSPLIT>
__device__ __forceinline__ void gcn_epilogue(
    f32x4* acc, const float* __restrict__ S, float* __restrict__ Out,
    int b, int chunk, int i0, int w, int fr, int g, int relu)
{
  const int rbase = i0 + (w << 4) + (g << 2);
  if constexpr (NSPLIT == 1) {
#pragma unroll
    for (int n = 0; n < 4; ++n) {
      const int col = (n << 4) | fr;
#pragma unroll
      for (int r = 0; r < 4; ++r) {
        const size_t idx = ((size_t)b * NN + (rbase + r)) * CC + col;
        float v = acc[n][r] + S[idx];
        if (relu) v = fmaxf(v, 0.f);
        Out[idx] = v;
      }
    }
  } else {
    float* P = Out + ((size_t)(chunk * 8 + b) * NN) * CC;
#pragma unroll
    for (int n = 0; n < 4; ++n) {
      const int col = (n << 4) | fr;
#pragma unroll
      for (int r = 0; r < 4; ++r)
        P[(size_t)(rbase + r) * CC + col] = acc[n][r];
    }
  }
}

// ---- GEMM, fp32 A: fully-unrolled K-loop, static ring buffers (A depth-4, B depth-2) ----
template<int NSPLIT>
__global__ __launch_bounds__(256) void gcn_gemm_f32(
    const float* __restrict__ A, const unsigned short* __restrict__ Mt,
    const float* __restrict__ S, float* __restrict__ Out,
    unsigned short* __restrict__ Abf, const int relu)
{
  constexpr int ITERS = NN / (64 * NSPLIT);
  const int bid = blockIdx.x;
  const int b   = bid & 7;                 // batch == XCD (Mt L2 locality)
  const int idx = bid >> 3;
  const int i0  = (idx & 31) << 6;
  const int chunk = idx >> 5;
  const int j0base = chunk * (NN / NSPLIT);
  const int tid = threadIdx.x, lane = tid & 63, w = tid >> 6;
  const int fr = lane & 15, g = lane >> 4;
  const int row = i0 + (w << 4) + fr;

  const float* ap = A + ((size_t)b * NN + row) * NN + j0base + (g << 3);
  const unsigned short* Mb = Mt + (size_t)b * CC * NN + (size_t)fr * NN + j0base + (g << 3);
  const bool wr = (Abf != nullptr);
  unsigned short* abp = wr ? (Abf + ((size_t)b * NN + row) * NN + j0base + (g << 3)) : nullptr;

#define LOAD_A(DST, T) do {                                          \
    const float* q_ = ap + (size_t)(T) * 64;                         \
    (DST)[0] = *reinterpret_cast<const float4*>(q_ + 0);             \
    (DST)[1] = *reinterpret_cast<const float4*>(q_ + 4);             \
    (DST)[2] = *reinterpret_cast<const float4*>(q_ + 32);            \
    (DST)[3] = *reinterpret_cast<const float4*>(q_ + 36);            \
  } while (0)
#define LOAD_B(DST, T) do {                                          \
    const unsigned short* mq_ = Mb + ((T) << 6);                     \
    _Pragma("unroll")                                                \
    for (int kk_ = 0; kk_ < 2; ++kk_)                                \
      _Pragma("unroll")                                              \
      for (int n_ = 0; n_ < 4; ++n_)                                 \
        (DST)[kk_ * 4 + n_] = *reinterpret_cast<const bf16x8*>(      \
            mq_ + (size_t)(n_ << 4) * NN + (kk_ << 5));              \
  } while (0)

  f32x4 acc[4];
#pragma unroll
  for (int n = 0; n < 4; ++n) acc[n] = (f32x4){0.f, 0.f, 0.f, 0.f};

  float4 Ar[4][4];
  bf16x8 Br[2][8];

  // prologue: interleaved issue, depth-4 A / depth-2 B
  LOAD_A(Ar[0], 0); LOAD_B(Br[0], 0);
  LOAD_A(Ar[1], 1); LOAD_B(Br[1], 1);
  LOAD_A(Ar[2], 2); LOAD_A(Ar[3], 3);

#pragma unroll
  for (int t = 0; t < ITERS; ++t) {
    bf16x8 af[2];
#pragma unroll
    for (int kk = 0; kk < 2; ++kk) {
      const float4 lo = Ar[t & 3][2 * kk + 0];
      const float4 hi = Ar[t & 3][2 * kk + 1];
      af[kk][0] = (short)f2bf(lo.x); af[kk][1] = (short)f2bf(lo.y);
      af[kk][2] = (short)f2bf(lo.z); af[kk][3] = (short)f2bf(lo.w);
      af[kk][4] = (short)f2bf(hi.x); af[kk][5] = (short)f2bf(hi.y);
      af[kk][6] = (short)f2bf(hi.z); af[kk][7] = (short)f2bf(hi.w);
    }
    if (wr) {
      *reinterpret_cast<bf16x8*>(abp + t * 64)      = af[0];
      *reinterpret_cast<bf16x8*>(abp + t * 64 + 32) = af[1];
    }
    if (t + 4 < ITERS) LOAD_A(Ar[t & 3], t + 4);   // static slot after consumption
#pragma unroll
    for (int kk = 0; kk < 2; ++kk)
#pragma unroll
      for (int n = 0; n < 4; ++n)
        acc[n] = __builtin_amdgcn_mfma_f32_16x16x32_bf16(af[kk], Br[t & 1][kk * 4 + n], acc[n], 0, 0, 0);
    if (t + 2 < ITERS) LOAD_B(Br[t & 1], t + 2);
  }
#undef LOAD_A
#undef LOAD_B

  gcn_epilogue<NSPLIT>(acc, S, Out, b, chunk, i0, w, fr, g, relu);
}

// ---- GEMM, bf16 A (layers 1,2): same static-ring pipeline ----
template<int NSPLIT>
__global__ __launch_bounds__(256) void gcn_gemm_bf16(
    const unsigned short* __restrict__ Abf, const unsigned short* __restrict__ Mt,
    const float* __restrict__ S, float* __restrict__ Out, const int relu)
{
  constexpr int ITERS = NN / (64 * NSPLIT);
  const int bid = blockIdx.x;
  const int b   = bid & 7;
  const int idx = bid >> 3;
  const int i0  = (idx & 31) << 6;
  const int chunk = idx >> 5;
  const int j0base = chunk * (NN / NSPLIT);
  const int tid = threadIdx.x, lane = tid & 63, w = tid >> 6;
  const int fr = lane & 15, g = lane >> 4;
  const int row = i0 + (w << 4) + fr;

  const unsigned short* ap = Abf + ((size_t)b * NN + row) * NN + j0base + (g << 3);
  const unsigned short* Mb = Mt + (size_t)b * CC * NN + (size_t)fr * NN + j0base + (g << 3);

#define LOAD_A(DST, T) do {                                          \
    const unsigned short* q_ = ap + (size_t)(T) * 64;                \
    (DST)[0] = *reinterpret_cast<const bf16x8*>(q_ + 0);             \
    (DST)[1] = *reinterpret_cast<const bf16x8*>(q_ + 32);            \
  } while (0)
#define LOAD_B(DST, T) do {                                          \
    const unsigned short* mq_ = Mb + ((T) << 6);                     \
    _Pragma("unroll")                                                \
    for (int kk_ = 0; kk_ < 2; ++kk_)                                \
      _Pragma("unroll")                                              \
      for (int n_ = 0; n_ < 4; ++n_)                                 \
        (DST)[kk_ * 4 + n_] = *reinterpret_cast<const bf16x8*>(      \
            mq_ + (size_t)(n_ << 4) * NN + (kk_ << 5));              \
  } while (0)

  f32x4 acc[4];
#pragma unroll
  for (int n = 0; n < 4; ++n) acc[n] = (f32x4){0.f, 0.f, 0.f, 0.f};

  bf16x8 Ar[4][2];
  bf16x8 Br[2][8];

  LOAD_A(Ar[0], 0); LOAD_B(Br[0], 0);
  LOAD_A(Ar[1], 1); LOAD_B(Br[1], 1);
  LOAD_A(Ar[2], 2); LOAD_A(Ar[3], 3);

#pragma unroll
  for (int t = 0; t < ITERS; ++t) {
#pragma unroll
    for (int kk = 0; kk < 2; ++kk)
#pragma unroll
      for (int n = 0; n < 4; ++n)
        acc[n] = __builtin_amdgcn_mfma_f32_16x16x32_bf16(Ar[t & 3][kk], Br[t & 1][kk * 4 + n], acc[n], 0, 0, 0);
    if (t + 4 < ITERS) LOAD_A(Ar[t & 3], t + 4);
    if (t + 2 < ITERS) LOAD_B(Br[t & 1], t + 2);
  }
#undef LOAD_A
#undef LOAD_B

  gcn_epilogue<NSPLIT>(acc, S, Out, b, chunk, i0, w, fr, g, relu);
}

extern "C" void kernel_launch(void* const* d_in, const int* in_sizes, int n_in,
                              void* d_out, int out_size, void* d_ws, size_t ws_size,
                              hipStream_t stream)
{
  const float* X = (const float*)d_in[0];
  const float* A = (const float*)d_in[1];
  const size_t MB = 1024 * 1024;
  unsigned short* Mt = (unsigned short*)d_ws;                 // 2 MiB
  float* S   = (float*)((char*)d_ws + 2 * MB);                // 4 MiB
  float* Prt = (float*)((char*)d_ws + 6 * MB);                // 16 MiB (4 chunks)
  unsigned short* Abf = (unsigned short*)((char*)d_ws + 22 * MB); // 64 MiB

  const bool has_part = ws_size >= 22 * MB;
  const bool has_abf  = ws_size >= 86 * MB;

  if (has_part) {
    for (int l = 0; l < 3; ++l) {
      const float* Wm = (const float*)d_in[2 + 3 * l];
      const float* Ws = (const float*)d_in[3 + 3 * l];
      const float* bb = (const float*)d_in[4 + 3 * l];
      if (l == 0)
        gcn_linear<<<dim3(256), dim3(256), 0, stream>>>(X, Wm, Ws, bb, Mt, S);
      else
        gcn_linear_fused<<<dim3(256), dim3(256), 0, stream>>>(Prt, S, Wm, Ws, bb, Mt, S);
      if (l == 0 && has_abf)
        gcn_gemm_f32<4><<<dim3(1024), dim3(256), 0, stream>>>(A, Mt, S, Prt, Abf, 0);
      else if (has_abf)
        gcn_gemm_bf16<4><<<dim3(1024), dim3(256), 0, stream>>>(Abf, Mt, S, Prt, 0);
      else
        gcn_gemm_f32<4><<<dim3(1024), dim3(256), 0, stream>>>(A, Mt, S, Prt, nullptr, 0);
    }
    gcn_finalize<<<dim3(1024), dim3(256), 0, stream>>>(Prt, S, (float*)d_out);
  } else {
    float* H = (float*)d_out;
    for (int l = 0; l < 3; ++l) {
      const float* Wm = (const float*)d_in[2 + 3 * l];
      const float* Ws = (const float*)d_in[3 + 3 * l];
      const float* bb = (const float*)d_in[4 + 3 * l];
      const float* src = (l == 0) ? X : H;
      gcn_linear<<<dim3(256), dim3(256), 0, stream>>>(src, Wm, Ws, bb, Mt, S);
      gcn_gemm_f32<1><<<dim3(256), dim3(256), 0, stream>>>(
          A, Mt, S, H, nullptr, (l < 2) ? 1 : 0);
    }
  }
}

// Round 5
// 148.014 us; speedup vs baseline: 1.1623x; 1.1515x over previous
//
#include <hip/hip_runtime.h>

typedef float  f32x4  __attribute__((ext_vector_type(4)));
typedef short  bf16x8 __attribute__((ext_vector_type(8)));

#define NN 2048
#define CC 64

#define WAITVM(N) asm volatile("s_waitcnt vmcnt(" #N ")" ::: "memory")
#define LGKM0     asm volatile("s_waitcnt lgkmcnt(0)" ::: "memory")

__device__ __forceinline__ unsigned short f2bf(float f) {
  union { float f; unsigned u; } v; v.f = f;
  unsigned r = v.u + 0x7fffu + ((v.u >> 16) & 1u);
  return (unsigned short)(r >> 16);
}

// async global->LDS, 16B per lane; dest = wave-uniform base + lane*16 (HW rule)
__device__ __forceinline__ void gll16(const void* g, void* l) {
  __builtin_amdgcn_global_load_lds(
      (const __attribute__((address_space(1))) unsigned int*)g,
      (__attribute__((address_space(3))) unsigned int*)l, 16, 0, 0);
}

// ---------------- per-layer linear: Mt = (H*Wm^T)^T bf16, S = H*Ws^T + b ----------------
__global__ __launch_bounds__(256) void gcn_linear(
    const float* __restrict__ H, const float* __restrict__ Wm,
    const float* __restrict__ Ws, const float* __restrict__ bias,
    unsigned short* __restrict__ Mt, float* __restrict__ S)
{
  const int bid = blockIdx.x;
  const int b   = bid >> 5;
  const int n0  = (bid & 31) << 6;
  const int tid = threadIdx.x;

  __shared__ float4 Hl[1024];
  __shared__ float4 Wm4[1024];
  __shared__ float4 Ws4[1024];

  const float4* Hg  = reinterpret_cast<const float4*>(H + ((size_t)b * NN + n0) * CC);
  const float4* Wmg = reinterpret_cast<const float4*>(Wm);
  const float4* Wsg = reinterpret_cast<const float4*>(Ws);
#pragma unroll
  for (int i = 0; i < 4; ++i) {
    int f = tid + 256 * i;
    Hl[f] = Hg[f];
    int o = f >> 4, c4 = f & 15;
    int slot = (o << 4) | (c4 ^ (o & 15));
    Wm4[slot] = Wmg[f];
    Ws4[slot] = Wsg[f];
  }
  __syncthreads();

  const int o = tid & 63, wv = tid >> 6;
  float accm[16], accs[16];
#pragma unroll
  for (int p = 0; p < 16; ++p) { accm[p] = 0.f; accs[p] = 0.f; }

  for (int c4 = 0; c4 < 16; ++c4) {
    int slot = (o << 4) | (c4 ^ (o & 15));
    float4 wm  = Wm4[slot];
    float4 wsv = Ws4[slot];
#pragma unroll
    for (int p = 0; p < 16; ++p) {
      float4 h = Hl[((wv << 4) + p) * 16 + c4];
      accm[p] += h.x * wm.x  + h.y * wm.y  + h.z * wm.z  + h.w * wm.w;
      accs[p] += h.x * wsv.x + h.y * wsv.y + h.z * wsv.z + h.w * wsv.w;
    }
  }

  const float bv = bias[o];
#pragma unroll
  for (int p = 0; p < 16; ++p) {
    int r = n0 + (wv << 4) + p;
    Mt[((size_t)b * CC + o) * NN + r] = f2bf(accm[p]);
    S [((size_t)b * NN + r) * CC + o] = accs[p] + bv;
  }
}

// ---------------- GEMM: H = relu?(A @ M + S) ----------------
// block = 16 output rows x 8 waves; wave w owns j-chunk [w*256, w*256+256), ITERS=4 K-tiles.
// Per-wave private LDS ring (depth 2), staged via global_load_lds, synced ONLY by counted
// vmcnt (no barriers in loop). LDS cross-wave reduction at the end; writes H directly.
// DT=0: fp32 A in, bf16 tiled Abf out. DT=1: bf16 tiled Abf in. DT=2: fp32 A, no store.
template<int DT>
__global__ __launch_bounds__(512) void gcn_gemm(
    const float* __restrict__ A, unsigned short* __restrict__ Abf,
    const unsigned short* __restrict__ Mt, const float* __restrict__ S,
    float* __restrict__ H, const int relu)
{
  constexpr int TILEB = (DT == 1) ? 2048 : 4096;
  __shared__ char smem[(DT == 1) ? 32768 : 65536];

  const int bid = blockIdx.x;
  const int b   = bid & 7;          // batch == XCD (Mt L2 locality)
  const int rb  = bid >> 3;
  const int n0  = rb << 4;          // 16 rows per block
  const int tid  = threadIdx.x;
  const int w    = tid >> 6;
  const int lane = tid & 63;
  const int fr   = lane & 15, g = lane >> 4;
  const int j0   = w << 8;          // 256-wide j-chunk per wave

  char* ring = smem + w * 2 * TILEB;

  const float* Ag = A + ((size_t)(b * NN + n0)) * NN + j0;
  const size_t wgid = (size_t)bid * 8 + w;
  const unsigned short* Mb = Mt + ((size_t)b * CC + fr) * NN + j0 + (g << 3);
  unsigned short* abw = Abf + wgid * 4096 + (size_t)lane * 8;  // tiled bf16-A stream

  // stage K-tile t into ring slot s (wave-private, no VGPR round trip)
  auto issueA = [&](int t, int s) {
    if constexpr (DT == 1) {
      const unsigned short* src = Abf + wgid * 4096 + (size_t)t * 1024 + lane * 8;
      gll16(src,       ring + s * TILEB);
      gll16(src + 512, ring + s * TILEB + 1024);
    } else {
      const int rl = lane >> 4, cl = lane & 15;
#pragma unroll
      for (int q = 0; q < 4; ++q) {
        int row = (q << 2) + rl;
        int c16 = cl ^ (row & 7);               // pre-swizzled source (T21)
        gll16(Ag + (size_t)row * NN + t * 64 + c16 * 4,
              ring + s * TILEB + (q << 10));    // linear LDS dest
      }
    }
  };

  auto loadB = [&](bf16x8* Bv, int t) {
#pragma unroll
    for (int kk = 0; kk < 2; ++kk)
#pragma unroll
      for (int n = 0; n < 4; ++n)
        Bv[kk * 4 + n] = *reinterpret_cast<const bf16x8*>(
            Mb + (size_t)(n << 4) * NN + t * 64 + (kk << 5));
  };

  // read A-fragments of slot s; LGKM0 before caller re-stages this slot
  auto readA = [&](int s, int t, bf16x8* af) {
    if constexpr (DT == 1) {
      af[0] = *reinterpret_cast<const bf16x8*>(ring + s * TILEB + lane * 16);
      af[1] = *reinterpret_cast<const bf16x8*>(ring + s * TILEB + 1024 + lane * 16);
      LGKM0;
      (void)t;
    } else {
      const float4* sh = reinterpret_cast<const float4*>(ring + s * TILEB);
      float4 v[4];
#pragma unroll
      for (int kk = 0; kk < 2; ++kk) {
        v[2 * kk]     = sh[(fr << 4) + (((kk << 3) + (g << 1))     ^ (fr & 7))];
        v[2 * kk + 1] = sh[(fr << 4) + (((kk << 3) + (g << 1) + 1) ^ (fr & 7))];
      }
      LGKM0;
#pragma unroll
      for (int kk = 0; kk < 2; ++kk) {
        af[kk][0] = (short)f2bf(v[2 * kk].x);     af[kk][1] = (short)f2bf(v[2 * kk].y);
        af[kk][2] = (short)f2bf(v[2 * kk].z);     af[kk][3] = (short)f2bf(v[2 * kk].w);
        af[kk][4] = (short)f2bf(v[2 * kk + 1].x); af[kk][5] = (short)f2bf(v[2 * kk + 1].y);
        af[kk][6] = (short)f2bf(v[2 * kk + 1].z); af[kk][7] = (short)f2bf(v[2 * kk + 1].w);
      }
      if constexpr (DT == 0) {
        *reinterpret_cast<bf16x8*>(abw + t * 1024)       = af[0];
        *reinterpret_cast<bf16x8*>(abw + t * 1024 + 512) = af[1];
      }
    }
  };

  f32x4 acc[4];
#pragma unroll
  for (int n = 0; n < 4; ++n) acc[n] = (f32x4){0.f, 0.f, 0.f, 0.f};

  auto mfma8 = [&](bf16x8* af, bf16x8* Bv) {
#pragma unroll
    for (int kk = 0; kk < 2; ++kk)
#pragma unroll
      for (int n = 0; n < 4; ++n)
        acc[n] = __builtin_amdgcn_mfma_f32_16x16x32_bf16(af[kk], Bv[kk * 4 + n], acc[n], 0, 0, 0);
  };

  bf16x8 B0[8], B1[8], B2[8], B3[8], af[2];

  // prologue: B(0) regs; A tiles 0,1 in flight
  loadB(B0, 0);
  issueA(0, 0); issueA(1, 1);

  // ---- t0: newer-than-A0 = A1 (4 gll f32 / 2 gll bf16) ----
  if constexpr (DT == 1) { WAITVM(2); } else { WAITVM(4); }
  readA(0, 0, af); loadB(B1, 1); issueA(2, 0); mfma8(af, B0);

  // ---- t1: newer-than-A1 = iter0 region {B1, (stores), A2} ----
  if constexpr (DT == 0) { WAITVM(14); } else if constexpr (DT == 2) { WAITVM(12); } else { WAITVM(10); }
  readA(1, 1, af); loadB(B2, 2); issueA(3, 1); mfma8(af, B1);

  // ---- t2: newer-than-A2 = iter1 region {B2, (stores), A3} ----
  if constexpr (DT == 0) { WAITVM(14); } else if constexpr (DT == 2) { WAITVM(12); } else { WAITVM(10); }
  readA(0, 2, af); loadB(B3, 3); mfma8(af, B2);

  // ---- t3: newer-than-A3 = iter2 region {B3, (stores)} ----
  if constexpr (DT == 0) { WAITVM(10); } else { WAITVM(8); }
  readA(1, 3, af); mfma8(af, B3);

  // ---- cross-wave reduction (alias ring memory; all gll drained by t3 wait) ----
  __syncthreads();
  float* red = reinterpret_cast<float*>(smem);   // [8 waves][16 rows][64 cols]
#pragma unroll
  for (int n = 0; n < 4; ++n)
#pragma unroll
    for (int r = 0; r < 4; ++r)
      red[(w << 10) + (((g << 2) + r) << 6) + (n << 4) + fr] = acc[n][r];
  __syncthreads();
  {
    const int row = tid >> 5;
    const int col = (tid & 31) << 1;
    float2 v = make_float2(0.f, 0.f);
#pragma unroll
    for (int ww = 0; ww < 8; ++ww) {
      float2 p = *reinterpret_cast<const float2*>(&red[(ww << 10) + (row << 6) + col]);
      v.x += p.x; v.y += p.y;
    }
    const size_t idx = ((size_t)b * NN + n0 + row) * CC + col;
    float2 s = *reinterpret_cast<const float2*>(&S[idx]);
    v.x += s.x; v.y += s.y;
    if (relu) { v.x = fmaxf(v.x, 0.f); v.y = fmaxf(v.y, 0.f); }
    *reinterpret_cast<float2*>(&H[idx]) = v;
  }
}

extern "C" void kernel_launch(void* const* d_in, const int* in_sizes, int n_in,
                              void* d_out, int out_size, void* d_ws, size_t ws_size,
                              hipStream_t stream)
{
  const float* X = (const float*)d_in[0];
  const float* A = (const float*)d_in[1];
  const size_t MB = 1024 * 1024;
  unsigned short* Mt  = (unsigned short*)d_ws;                      // 2 MiB
  float*          S   = (float*)((char*)d_ws + 2 * MB);             // 4 MiB
  unsigned short* Abf = (unsigned short*)((char*)d_ws + 6 * MB);    // 64 MiB bf16 tiled A
  const bool has_abf = ws_size >= 70 * MB;
  float* H = (float*)d_out;

  for (int l = 0; l < 3; ++l) {
    const float* Wm = (const float*)d_in[2 + 3 * l];
    const float* Ws = (const float*)d_in[3 + 3 * l];
    const float* bb = (const float*)d_in[4 + 3 * l];
    const int relu = (l < 2) ? 1 : 0;
    gcn_linear<<<dim3(256), dim3(256), 0, stream>>>((l == 0) ? X : H, Wm, Ws, bb, Mt, S);
    if (has_abf) {
      if (l == 0)
        gcn_gemm<0><<<dim3(1024), dim3(512), 0, stream>>>(A, Abf, Mt, S, H, relu);
      else
        gcn_gemm<1><<<dim3(1024), dim3(512), 0, stream>>>(A, Abf, Mt, S, H, relu);
    } else {
      gcn_gemm<2><<<dim3(1024), dim3(512), 0, stream>>>(A, (unsigned short*)d_ws, Mt, S, H, relu);
    }
  }
}